// Round 9
// baseline (176.213 us; speedup 1.0000x reference)
//
#include <hip/hip_runtime.h>
#include <hip/hip_bf16.h>

// Problem constants
#define B_  16
#define L_  512
#define D_  1024
#define H_  16
#define DH_ 64
#define NEG_ (-1e9f)
#define QB_ 64
#define KB_ 64
#define LDP 72    // padded LDS row (bf16) for attention tiles

#define GK  1024  // K dim of both GEMMs
#define NKT 16    // GK/64 K-tiles for the BK=64 pipelined GEMM

typedef unsigned short ushort_t;
typedef __attribute__((ext_vector_type(8))) short bf16x8;
typedef __attribute__((ext_vector_type(4))) float f32x4;

__device__ __forceinline__ ushort_t f2bf(float f) {
    unsigned u = __float_as_uint(f);
    u += 0x7FFFu + ((u >> 16) & 1u);   // round-to-nearest-even
    return (ushort_t)(u >> 16);
}
__device__ __forceinline__ unsigned packbf(float a, float b) {
    return (unsigned)f2bf(a) | ((unsigned)f2bf(b) << 16);
}

__device__ __forceinline__ void gload_lds16(const void* g, void* l) {
    __builtin_amdgcn_global_load_lds(
        (const __attribute__((address_space(1))) void*)g,
        (__attribute__((address_space(3))) void*)l, 16, 0, 0);
}

// ---------------------------------------------------------------------------
// Merged prep: x f32->bf16  +  transpose Wqkv  +  transpose Wfc (one dispatch)
// grid = 8192 (conv) + 4096 (Wqkv 128x32 tiles) + 1024 (Wfc 32x32 tiles)
// ---------------------------------------------------------------------------
__global__ __launch_bounds__(256) void prep_all(const float* __restrict__ x,
                                                const float* __restrict__ Wqkv,
                                                const float* __restrict__ Wfc,
                                                ushort_t* __restrict__ xbf,
                                                ushort_t* __restrict__ WqT,
                                                ushort_t* __restrict__ WfT) {
    __shared__ float tile[32][33];
    const int bid = blockIdx.x;
    const int t   = threadIdx.x;

    if (bid < 8192) {   // conv x -> xbf (block-uniform branch)
        const int i = (bid * 256 + t) * 4;
        const float4 v = *(const float4*)&x[i];
        ushort4 o;
        o.x = f2bf(v.x); o.y = f2bf(v.y); o.z = f2bf(v.z); o.w = f2bf(v.w);
        *(ushort4*)&xbf[i] = o;
        return;
    }
    const float* src; ushort_t* dst; int C, gx, gy;
    if (bid < 8192 + 4096) {
        const int lb = bid - 8192;
        src = Wqkv; dst = WqT; C = 4096; gx = lb & 127; gy = lb >> 7;
    } else {
        const int lb = bid - 12288;
        src = Wfc;  dst = WfT; C = 1024; gx = lb & 31;  gy = lb >> 5;
    }
    const int R  = 1024;
    const int r0 = gy * 32, c0 = gx * 32;
    const int tr = t >> 3, tc = (t & 7) * 4;
    const float4 v = *(const float4*)&src[(size_t)(r0 + tr) * C + c0 + tc];
    tile[tr][tc + 0] = v.x;
    tile[tr][tc + 1] = v.y;
    tile[tr][tc + 2] = v.z;
    tile[tr][tc + 3] = v.w;
    __syncthreads();
    ushort4 o;
    o.x = f2bf(tile[tc + 0][tr]);
    o.y = f2bf(tile[tc + 1][tr]);
    o.z = f2bf(tile[tc + 2][tr]);
    o.w = f2bf(tile[tc + 3][tr]);
    *(ushort4*)&dst[(size_t)(c0 + tr) * R + r0 + tc] = o;
}

// ---------------------------------------------------------------------------
// Stage-3 GEMM (128x128, BK=64, m97 structure) with row-XOR LDS swizzle:
// staging pre-swizzles the global source (gload_lds dest stays linear),
// frag reads apply the same XOR -> 8-lane/slot-group optimal ds_read_b128.
// C[M,N] = A[M,K] @ Bt[N,K]^T + bias (f32 out).
// ---------------------------------------------------------------------------
__global__ __launch_bounds__(256) void gemm_bf16_mfma(const ushort_t* __restrict__ A,
                                                      const ushort_t* __restrict__ Bt,
                                                      const float* __restrict__ bias,
                                                      float* __restrict__ C,
                                                      int M, int N, int K) {
    __shared__ __align__(16) ushort_t As[128 * 64];
    __shared__ __align__(16) ushort_t Bs[128 * 64];

    const int t    = threadIdx.x;
    const int wave = t >> 6;
    const int lane = t & 63;
    const int m0   = blockIdx.y * 128;
    const int n0   = blockIdx.x * 128;
    const int wr   = wave >> 1;
    const int wc   = wave & 1;

    const int lrow = lane >> 3;                     // 0..7 row within 8-row chunk
    const int ksl  = (lane & 7) ^ lrow;             // pre-swizzled source slot
    const int llo  = lane & 15;
    const int lhi  = lane >> 4;

    f32x4 acc[4][4] = {};

    for (int k0 = 0; k0 < K; k0 += 64) {
        #pragma unroll
        for (int i = 0; i < 4; ++i) {
            const int row = wave * 32 + i * 8;      // 8-row chunk base (mult of 8)
            gload_lds16(A + (size_t)(m0 + row + lrow) * K + k0 + ksl * 8,
                        As + (size_t)row * 64);
            gload_lds16(Bt + (size_t)(n0 + row + lrow) * K + k0 + ksl * 8,
                        Bs + (size_t)row * 64);
        }
        __syncthreads();

        #pragma unroll
        for (int ks = 0; ks < 2; ++ks) {
            bf16x8 af[4], bfr[4];
            #pragma unroll
            for (int m = 0; m < 4; ++m) {
                const int row = wr * 64 + m * 16 + llo;
                af[m] = *(const bf16x8*)&As[row * 64 + (((ks * 4 + lhi) ^ (row & 7)) << 3)];
            }
            #pragma unroll
            for (int n = 0; n < 4; ++n) {
                const int row = wc * 64 + n * 16 + llo;
                bfr[n] = *(const bf16x8*)&Bs[row * 64 + (((ks * 4 + lhi) ^ (row & 7)) << 3)];
            }
            #pragma unroll
            for (int m = 0; m < 4; ++m)
                #pragma unroll
                for (int n = 0; n < 4; ++n)
                    acc[m][n] = __builtin_amdgcn_mfma_f32_16x16x32_bf16(
                        af[m], bfr[n], acc[m][n], 0, 0, 0);
        }
        __syncthreads();
    }

    #pragma unroll
    for (int m = 0; m < 4; ++m) {
        #pragma unroll
        for (int n = 0; n < 4; ++n) {
            const int col = n0 + wc * 64 + n * 16 + llo;
            const float bv = bias[col];
            #pragma unroll
            for (int i = 0; i < 4; ++i) {
                const int row = m0 + wr * 64 + m * 16 + lhi * 4 + i;
                C[(size_t)row * N + col] = acc[m][n][i] + bv;
            }
        }
    }
}

// ---------------------------------------------------------------------------
// Stage-1 GEMM: 128x256 tile, BK=64 (128B LDS rows -> 8-slot optimal reads),
// 3-buffer ring (144 KB), 2-tile-ahead prefetch, counted vmcnt(6) (never 0
// in main loop), free-running waves + setprio, XOR swizzle both sides,
// XCD-aware block swizzle.  C bf16 out.  K fixed = GK.
// 512 threads = 8 waves (2 row x 4 col), per-wave output 64x64 (4x4 frags).
// Ring safety: stage kt+2 targets buf (kt+2)%3 = buf of kt-1, whose reads
// finished at the barrier ending kt-1; vmcnt(6) at kt end ensures kt+1's
// 6 loads landed while kt+2's 6 stay in flight.
// ---------------------------------------------------------------------------
__global__ __launch_bounds__(512, 2) void gemm128x256(const ushort_t* __restrict__ A,
                                                      const ushort_t* __restrict__ Bt,
                                                      ushort_t* __restrict__ C,
                                                      int nbn, int N) {
    extern __shared__ __align__(16) ushort_t lds[];   // 3 x (A 8192 + B 16384) ushorts

    const int t    = threadIdx.x;
    const int wave = t >> 6;
    const int lane = t & 63;
    const int wr   = wave >> 2;       // 0..1
    const int wc   = wave & 3;        // 0..3
    const int lhi  = lane >> 4;       // 0..3
    const int llo  = lane & 15;       // 0..15

    // XCD-aware bijective swizzle (grid % 8 == 0)
    const int cpx = gridDim.x >> 3;
    const int swz = (blockIdx.x & 7) * cpx + (blockIdx.x >> 3);
    const int m0  = (swz / nbn) * 128;
    const int n0  = (swz % nbn) * 256;

    // stage A tile (128x64, 2 loads/thread) / B tile (256x64, 4 loads/thread)
    #define STAGE_A(buf, kt)                                                     \
        _Pragma("unroll")                                                        \
        for (int j = 0; j < 2; ++j) {                                            \
            const int row_ = (j * 512 + t) >> 3;                                 \
            const int ks_  = (t & 7) ^ (row_ & 7);                               \
            gload_lds16(A + (size_t)(m0 + row_) * GK + (kt) * 64 + ks_ * 8,      \
                        lds + (buf) * 24576 + j * 4096 + (t >> 6) * 512);        \
        }
    #define STAGE_B(buf, kt)                                                     \
        _Pragma("unroll")                                                        \
        for (int j = 0; j < 4; ++j) {                                            \
            const int row_ = (j * 512 + t) >> 3;                                 \
            const int ks_  = (t & 7) ^ (row_ & 7);                               \
            gload_lds16(Bt + (size_t)(n0 + row_) * GK + (kt) * 64 + ks_ * 8,     \
                        lds + (buf) * 24576 + 8192 + j * 4096 + (t >> 6) * 512); \
        }

    f32x4 acc[4][4] = {};

    STAGE_A(0, 0); STAGE_B(0, 0);
    STAGE_A(1, 1); STAGE_B(1, 1);
    asm volatile("s_waitcnt vmcnt(6)" ::: "memory");   // kt0 landed, kt1 in flight
    __builtin_amdgcn_s_barrier();

    for (int kt = 0; kt < NKT; ++kt) {
        const ushort_t* Ab = lds + (kt % 3) * 24576;
        const ushort_t* Bb = Ab + 8192;

        bf16x8 afr[4][2], bfr[4][2];
        #pragma unroll
        for (int mi = 0; mi < 4; ++mi)
            #pragma unroll
            for (int kk = 0; kk < 2; ++kk) {
                const int row = wr * 64 + mi * 16 + llo;
                afr[mi][kk] = *(const bf16x8*)&Ab[row * 64 + (((kk * 4 + lhi) ^ (row & 7)) << 3)];
            }
        #pragma unroll
        for (int n = 0; n < 4; ++n)
            #pragma unroll
            for (int kk = 0; kk < 2; ++kk) {
                const int row = wc * 64 + n * 16 + llo;
                bfr[n][kk] = *(const bf16x8*)&Bb[row * 64 + (((kk * 4 + lhi) ^ (row & 7)) << 3)];
            }

        if (kt + 2 < NKT) { STAGE_A((kt + 2) % 3, kt + 2); STAGE_B((kt + 2) % 3, kt + 2); }

        __builtin_amdgcn_s_setprio(1);
        #pragma unroll
        for (int kk = 0; kk < 2; ++kk)
            #pragma unroll
            for (int mi = 0; mi < 4; ++mi)
                #pragma unroll
                for (int n = 0; n < 4; ++n)
                    acc[mi][n] = __builtin_amdgcn_mfma_f32_16x16x32_bf16(
                        afr[mi][kk], bfr[n][kk], acc[mi][n], 0, 0, 0);
        __builtin_amdgcn_s_setprio(0);

        if (kt + 2 < NKT)      { asm volatile("s_waitcnt vmcnt(6)" ::: "memory"); }
        else if (kt + 1 < NKT) { asm volatile("s_waitcnt vmcnt(0)" ::: "memory"); }
        __builtin_amdgcn_s_barrier();
    }
    #undef STAGE_A
    #undef STAGE_B

    // epilogue: C write (bf16)
    #pragma unroll
    for (int mi = 0; mi < 4; ++mi) {
        #pragma unroll
        for (int n = 0; n < 4; ++n) {
            const int col = n0 + wc * 64 + n * 16 + llo;
            #pragma unroll
            for (int i = 0; i < 4; ++i) {
                const int row = m0 + wr * 64 + mi * 16 + lhi * 4 + i;
                C[(size_t)row * N + col] = f2bf(acc[mi][n][i]);
            }
        }
    }
}

// ---------------------------------------------------------------------------
// MFMA fused attention, swapped-operand (S^T) form, Gaussian band skip +
// T14 async-STAGE (unchanged from round 7/8 — validated).
// ---------------------------------------------------------------------------
__global__ __launch_bounds__(256) void attn_mfma(const ushort_t* __restrict__ qkv,
                                                 const int* __restrict__ mask,
                                                 const int* __restrict__ qmask,
                                                 const float* __restrict__ shiftp,
                                                 const float* __restrict__ biasp,
                                                 const int* __restrict__ useg,
                                                 ushort_t* __restrict__ O) {
    __shared__ __align__(16) ushort_t K1s[KB_][LDP];
    __shared__ __align__(16) ushort_t K2s[KB_][LDP];
    __shared__ __align__(16) ushort_t Vt[DH_][LDP];    // [d][kv]
    __shared__ __align__(16) unsigned Ps32[QB_][36];   // P^T packed pairs / O out
    __shared__ __align__(16) int      Ms[L_];          // (qmask<<1)|mask per key

    const int t    = threadIdx.x;
    const int wave = t >> 6;
    const int lane = t & 63;
    const int lhi  = lane >> 4;     // 0..3
    const int llo  = lane & 15;     // 0..15

    // XCD-aware bijective swizzle (2048 % 8 == 0)
    const int orig = blockIdx.x;
    const int swz  = (orig & 7) * 256 + (orig >> 3);
    const int bh   = swz >> 3;            // 0..255
    const int qb   = swz & 7;             // 0..7
    const int b    = bh >> 4;
    const int h    = bh & 15;
    const int q0   = qb * QB_;

    const float shiftv = shiftp[0];
    const float biasv  = biasp[0];
    const int   useG   = useg[0];
    const size_t rowbase = (size_t)b * L_ * (4 * D_);
    const int    hoff    = h * DH_;

    {
        const int k = t;
        Ms[k]       = (qmask[b * L_ + k] << 1) | (mask[b * L_ + k] != 0 ? 1 : 0);
        Ms[k + 256] = (qmask[b * L_ + k + 256] << 1) | (mask[b * L_ + k + 256] != 0 ? 1 : 0);
    }

    const int gq = q0 + wave * 16 + llo;
    bf16x8 af_q[2];
    #pragma unroll
    for (int ks = 0; ks < 2; ++ks)
        af_q[ks] = *(const bf16x8*)&qkv[rowbase + (size_t)gq * (4 * D_) + hoff
                                        + ks * 32 + lhi * 8];
    const int qm_q = qmask[b * L_ + gq];

    // Gaussian band: contiguous surviving kt range [lo, hi]
    int lo = 0, hi = (L_ / KB_) - 1;
    if (useG) {
        while (lo < hi) {
            const int k0 = lo * KB_;
            int dmin = (k0 > q0) ? (k0 - (q0 + KB_ - 1)) : (q0 - (k0 + KB_ - 1));
            if (dmin < 0) dmin = 0;
            if (shiftv * (float)dmin * (float)dmin > 240.f) ++lo; else break;
        }
        while (hi > lo) {
            const int k0 = hi * KB_;
            int dmin = (k0 > q0) ? (k0 - (q0 + KB_ - 1)) : (q0 - (k0 + KB_ - 1));
            if (dmin < 0) dmin = 0;
            if (shiftv * (float)dmin * (float)dmin > 240.f) --hi; else break;
        }
    }

    float m_run = -1e30f, l_run = 0.f;
    f32x4 acc_o[4] = {};

    const int srow8 = t >> 3;
    const int scol8 = (t & 7) * 8;
    const int vkv   = t & 63;
    const int vd0   = (t >> 6) * 8;

    uint4 pk1[2], pk2[2], pvv[2];

    #define ISSUE_KV(kt_) do {                                                          \
        const int k0_ = (kt_) * KB_;                                                    \
        _Pragma("unroll")                                                               \
        for (int it = 0; it < 2; ++it) {                                                \
            const int row = srow8 + it * 32;                                            \
            const size_t gb = rowbase + (size_t)(k0_ + row) * (4 * D_) + hoff + scol8;  \
            pk1[it] = *(const uint4*)&qkv[gb + D_];                                     \
            pk2[it] = *(const uint4*)&qkv[gb + 2 * D_];                                 \
            const int d_ = vd0 + it * 32;                                               \
            pvv[it] = *(const uint4*)&qkv[rowbase + (size_t)(k0_ + vkv) * (4 * D_)      \
                                          + 3 * D_ + hoff + d_];                        \
        }                                                                               \
    } while (0)

    ISSUE_KV(lo);

    for (int kt = lo; kt <= hi; ++kt) {
        const int k0 = kt * KB_;

        #pragma unroll
        for (int it = 0; it < 2; ++it) {
            const int row = srow8 + it * 32;
            *(uint4*)&K1s[row][scol8] = pk1[it];
            *(uint4*)&K2s[row][scol8] = pk2[it];
            const int d = vd0 + it * 32;
            const uint4 raw = pvv[it];
            Vt[d + 0][vkv] = (ushort_t)(raw.x & 0xFFFFu);
            Vt[d + 1][vkv] = (ushort_t)(raw.x >> 16);
            Vt[d + 2][vkv] = (ushort_t)(raw.y & 0xFFFFu);
            Vt[d + 3][vkv] = (ushort_t)(raw.y >> 16);
            Vt[d + 4][vkv] = (ushort_t)(raw.z & 0xFFFFu);
            Vt[d + 5][vkv] = (ushort_t)(raw.z >> 16);
            Vt[d + 6][vkv] = (ushort_t)(raw.w & 0xFFFFu);
            Vt[d + 7][vkv] = (ushort_t)(raw.w >> 16);
        }
        if (kt < hi) ISSUE_KV(kt + 1);
        __syncthreads();

        f32x4 s1[4], s2[4];
        #pragma unroll
        for (int n = 0; n < 4; ++n) { s1[n] = (f32x4){0,0,0,0}; s2[n] = (f32x4){0,0,0,0}; }
        #pragma unroll
        for (int ks = 0; ks < 2; ++ks) {
            const int kb = ks * 32 + lhi * 8;
            #pragma unroll
            for (int n = 0; n < 4; ++n) {
                const bf16x8 bk1 = *(const bf16x8*)&K1s[n * 16 + llo][kb];
                const bf16x8 bk2 = *(const bf16x8*)&K2s[n * 16 + llo][kb];
                s1[n] = __builtin_amdgcn_mfma_f32_16x16x32_bf16(bk1, af_q[ks], s1[n], 0, 0, 0);
                s2[n] = __builtin_amdgcn_mfma_f32_16x16x32_bf16(bk2, af_q[ks], s2[n], 0, 0, 0);
            }
        }

        float sv[4][4];
        float mx = -1e30f;
        #pragma unroll
        for (int n = 0; n < 4; ++n) {
            const int4 mc = *(const int4*)&Ms[k0 + n * 16 + lhi * 4];
            const int mci[4] = {mc.x, mc.y, mc.z, mc.w};
            #pragma unroll
            for (int i = 0; i < 4; ++i) {
                const int key = k0 + n * 16 + lhi * 4 + i;
                float x = ((mci[i] >> 1) == qm_q) ? s1[n][i] : s2[n][i];
                if (!(mci[i] & 1)) x = NEG_;
                if (useG) {
                    const float dq = (float)(gq - key);
                    x -= shiftv * dq * dq + biasv;
                }
                sv[n][i] = x;
                mx = fmaxf(mx, x);
            }
        }
        mx = fmaxf(mx, __shfl_xor(mx, 16));
        mx = fmaxf(mx, __shfl_xor(mx, 32));

        const float m_new = fmaxf(m_run, mx);
        const float scale = __expf(m_run - m_new);

        float p[4][4], ls = 0.f;
        #pragma unroll
        for (int n = 0; n < 4; ++n)
            #pragma unroll
            for (int i = 0; i < 4; ++i) {
                p[n][i] = __expf(sv[n][i] - m_new);
                ls += p[n][i];
            }
        ls += __shfl_xor(ls, 16);
        ls += __shfl_xor(ls, 32);
        l_run = l_run * scale + ls;
        m_run = m_new;

        #pragma unroll
        for (int n2 = 0; n2 < 4; ++n2) {
            acc_o[n2][0] *= scale; acc_o[n2][1] *= scale;
            acc_o[n2][2] *= scale; acc_o[n2][3] *= scale;
        }

        const int qrow = wave * 16 + llo;
        #pragma unroll
        for (int n = 0; n < 4; ++n) {
            uint2 w;
            w.x = packbf(p[n][0], p[n][1]);
            w.y = packbf(p[n][2], p[n][3]);
            *(uint2*)&Ps32[qrow][n * 8 + lhi * 2] = w;
        }

        #pragma unroll
        for (int ks = 0; ks < 2; ++ks) {
            const int kb = ks * 32 + lhi * 8;
            const bf16x8 bp = *(const bf16x8*)&Ps32[qrow][ks * 16 + lhi * 4];
            #pragma unroll
            for (int n2 = 0; n2 < 4; ++n2) {
                const bf16x8 av = *(const bf16x8*)&Vt[n2 * 16 + llo][kb];
                acc_o[n2] = __builtin_amdgcn_mfma_f32_16x16x32_bf16(av, bp, acc_o[n2], 0, 0, 0);
            }
        }
        __syncthreads();
    }
    #undef ISSUE_KV

    {
        const float inv = 1.f / l_run;
        const int qrow = wave * 16 + llo;
        #pragma unroll
        for (int n2 = 0; n2 < 4; ++n2) {
            uint2 w;
            w.x = packbf(acc_o[n2][0] * inv, acc_o[n2][1] * inv);
            w.y = packbf(acc_o[n2][2] * inv, acc_o[n2][3] * inv);
            *(uint2*)&Ps32[qrow][n2 * 8 + lhi * 2] = w;
        }
    }
    __syncthreads();
    {
        const int row = t >> 2;
        const int c4  = (t & 3) * 8;
        const uint4 a = *(const uint4*)&Ps32[row][c4];
        const uint4 b2 = *(const uint4*)&Ps32[row][c4 + 4];
        ushort_t* dst = &O[(size_t)(b * L_ + q0 + row) * D_ + hoff + c4 * 2];
        *(uint4*)dst       = a;
        *(uint4*)(dst + 8) = b2;
    }
}

// ---------------------------------------------------------------------------
// Launch
// ---------------------------------------------------------------------------
extern "C" void kernel_launch(void* const* d_in, const int* in_sizes, int n_in,
                              void* d_out, int out_size, void* d_ws, size_t ws_size,
                              hipStream_t stream) {
    const float* x      = (const float*)d_in[0];
    const int*   mask   = (const int*)d_in[1];
    const int*   qmask  = (const int*)d_in[2];
    const float* Wqkv   = (const float*)d_in[3];
    const float* Wfc    = (const float*)d_in[4];
    const float* bfc    = (const float*)d_in[5];
    const float* shift  = (const float*)d_in[6];
    const float* bias_p = (const float*)d_in[7];
    const int*   useg   = (const int*)d_in[8];
    float*       out    = (float*)d_out;

    const int M  = B_ * L_;         // 8192
    const int N1 = 4 * D_;          // 4096

    ushort_t* qkv = (ushort_t*)d_ws;
    ushort_t* Obf = qkv + (size_t)M * N1;
    ushort_t* xbf = Obf + (size_t)M * D_;
    ushort_t* WqT = xbf + (size_t)M * D_;
    ushort_t* WfT = WqT + (size_t)N1 * D_;

    // prep: conv + both weight transposes in one dispatch
    prep_all<<<dim3(8192 + 4096 + 1024), 256, 0, stream>>>(x, Wqkv, Wfc,
                                                           xbf, WqT, WfT);

    // Stage 1: qkv = x @ Wqkv — 128x256 BK=64 3-buffer pipelined kernel
    // grid = (8192/128)*(4096/256) = 1024 blocks; dynamic LDS = 144 KiB
    gemm128x256<<<dim3(1024), 512, 147456, stream>>>(xbf, WqT, qkv, N1 / 256, N1);

    // Stage 2: fused attention (Gaussian band + async-stage) -> Obf
    attn_mfma<<<dim3((B_ * H_) * (L_ / QB_)), 256, 0, stream>>>(qkv, mask, qmask,
                                                                shift, bias_p, useg, Obf);

    // Stage 3: out = Obf @ Wfc + bfc  (128x128 swizzled kernel: 512 blocks)
    gemm_bf16_mfma<<<dim3(D_ / 128, M / 128), 256, 0, stream>>>(
        Obf, WfT, bfc, out, M, D_, D_);
}

// Round 10
// 168.513 us; speedup vs baseline: 1.0457x; 1.0457x over previous
//
#include <hip/hip_runtime.h>
#include <hip/hip_bf16.h>

// Problem constants
#define B_  16
#define L_  512
#define D_  1024
#define H_  16
#define DH_ 64
#define NEG_ (-1e9f)
#define QB_ 64
#define KB_ 64
#define LDP 72    // padded LDS row (bf16) for attention tiles

#define GK  1024  // K dim of both GEMMs
#define NKT 16    // K-tiles (BK=64) for stage-1
#define NI  8     // iterations (2 K-tiles each)

typedef unsigned short ushort_t;
typedef __attribute__((ext_vector_type(8))) short bf16x8;
typedef __attribute__((ext_vector_type(4))) float f32x4;

__device__ __forceinline__ ushort_t f2bf(float f) {
    unsigned u = __float_as_uint(f);
    u += 0x7FFFu + ((u >> 16) & 1u);   // round-to-nearest-even
    return (ushort_t)(u >> 16);
}
__device__ __forceinline__ unsigned packbf(float a, float b) {
    return (unsigned)f2bf(a) | ((unsigned)f2bf(b) << 16);
}

__device__ __forceinline__ void gload_lds16(const void* g, void* l) {
    __builtin_amdgcn_global_load_lds(
        (const __attribute__((address_space(1))) void*)g,
        (__attribute__((address_space(3))) void*)l, 16, 0, 0);
}

// ---------------------------------------------------------------------------
// Merged prep: x f32->bf16  +  transpose Wqkv  +  transpose Wfc (one dispatch)
// ---------------------------------------------------------------------------
__global__ __launch_bounds__(256) void prep_all(const float* __restrict__ x,
                                                const float* __restrict__ Wqkv,
                                                const float* __restrict__ Wfc,
                                                ushort_t* __restrict__ xbf,
                                                ushort_t* __restrict__ WqT,
                                                ushort_t* __restrict__ WfT) {
    __shared__ float tile[32][33];
    const int bid = blockIdx.x;
    const int t   = threadIdx.x;

    if (bid < 8192) {   // conv x -> xbf
        const int i = (bid * 256 + t) * 4;
        const float4 v = *(const float4*)&x[i];
        ushort4 o;
        o.x = f2bf(v.x); o.y = f2bf(v.y); o.z = f2bf(v.z); o.w = f2bf(v.w);
        *(ushort4*)&xbf[i] = o;
        return;
    }
    const float* src; ushort_t* dst; int C, gx, gy;
    if (bid < 8192 + 4096) {
        const int lb = bid - 8192;
        src = Wqkv; dst = WqT; C = 4096; gx = lb & 127; gy = lb >> 7;
    } else {
        const int lb = bid - 12288;
        src = Wfc;  dst = WfT; C = 1024; gx = lb & 31;  gy = lb >> 5;
    }
    const int R  = 1024;
    const int r0 = gy * 32, c0 = gx * 32;
    const int tr = t >> 3, tc = (t & 7) * 4;
    const float4 v = *(const float4*)&src[(size_t)(r0 + tr) * C + c0 + tc];
    tile[tr][tc + 0] = v.x;
    tile[tr][tc + 1] = v.y;
    tile[tr][tc + 2] = v.z;
    tile[tr][tc + 3] = v.w;
    __syncthreads();
    ushort4 o;
    o.x = f2bf(tile[tc + 0][tr]);
    o.y = f2bf(tile[tc + 1][tr]);
    o.z = f2bf(tile[tc + 2][tr]);
    o.w = f2bf(tile[tc + 3][tr]);
    *(ushort4*)&dst[(size_t)(c0 + tr) * R + r0 + tc] = o;
}

// ---------------------------------------------------------------------------
// Stage-3 GEMM (128x128, BK=64) with row-XOR LDS swizzle (validated round 9).
// ---------------------------------------------------------------------------
__global__ __launch_bounds__(256) void gemm_bf16_mfma(const ushort_t* __restrict__ A,
                                                      const ushort_t* __restrict__ Bt,
                                                      const float* __restrict__ bias,
                                                      float* __restrict__ C,
                                                      int M, int N, int K) {
    __shared__ __align__(16) ushort_t As[128 * 64];
    __shared__ __align__(16) ushort_t Bs[128 * 64];

    const int t    = threadIdx.x;
    const int wave = t >> 6;
    const int lane = t & 63;
    const int m0   = blockIdx.y * 128;
    const int n0   = blockIdx.x * 128;
    const int wr   = wave >> 1;
    const int wc   = wave & 1;

    const int lrow = lane >> 3;
    const int ksl  = (lane & 7) ^ lrow;
    const int llo  = lane & 15;
    const int lhi  = lane >> 4;

    f32x4 acc[4][4] = {};

    for (int k0 = 0; k0 < K; k0 += 64) {
        #pragma unroll
        for (int i = 0; i < 4; ++i) {
            const int row = wave * 32 + i * 8;
            gload_lds16(A + (size_t)(m0 + row + lrow) * K + k0 + ksl * 8,
                        As + (size_t)row * 64);
            gload_lds16(Bt + (size_t)(n0 + row + lrow) * K + k0 + ksl * 8,
                        Bs + (size_t)row * 64);
        }
        __syncthreads();

        #pragma unroll
        for (int ks = 0; ks < 2; ++ks) {
            bf16x8 af[4], bfr[4];
            #pragma unroll
            for (int m = 0; m < 4; ++m) {
                const int row = wr * 64 + m * 16 + llo;
                af[m] = *(const bf16x8*)&As[row * 64 + (((ks * 4 + lhi) ^ (row & 7)) << 3)];
            }
            #pragma unroll
            for (int n = 0; n < 4; ++n) {
                const int row = wc * 64 + n * 16 + llo;
                bfr[n] = *(const bf16x8*)&Bs[row * 64 + (((ks * 4 + lhi) ^ (row & 7)) << 3)];
            }
            #pragma unroll
            for (int m = 0; m < 4; ++m)
                #pragma unroll
                for (int n = 0; n < 4; ++n)
                    acc[m][n] = __builtin_amdgcn_mfma_f32_16x16x32_bf16(
                        af[m], bfr[n], acc[m][n], 0, 0, 0);
        }
        __syncthreads();
    }

    #pragma unroll
    for (int m = 0; m < 4; ++m) {
        #pragma unroll
        for (int n = 0; n < 4; ++n) {
            const int col = n0 + wc * 64 + n * 16 + llo;
            const float bv = bias[col];
            #pragma unroll
            for (int i = 0; i < 4; ++i) {
                const int row = m0 + wr * 64 + m * 16 + lhi * 4 + i;
                C[(size_t)row * N + col] = acc[m][n][i] + bv;
            }
        }
    }
}

// ---------------------------------------------------------------------------
// Stage-1 GEMM: m201-style 256x256 8-phase schedule.  BK=64, 512 thr = 8
// waves (2Mx4N), LDS = 2 slots x {A,B} x 2 K-halves x 256x32 bf16 = 128 KB.
// Sub-buffer idx = ((slot*2 + mat)*2 + khalf) * 8192 elems.
// Per iteration (2 K-tiles: E=2i slot0, O=2i+1 slot1), 8 phases, each:
//   [ds_read frags | issue half-tile stage] -> s_barrier -> lgkmcnt(0) ->
//   setprio(1) 16 MFMA setprio(0) -> [counted vmcnt] -> s_barrier
// Stage stagger (target freed 1+ phases earlier; LDS[r][sl]=G[r][sl^((r>>1)&3)]):
//   P1: s1k1(O)  P2: s0Bk0(E+2)  P3: s0Ak0(E+2)  P5: s0k1(E+2)
//   P6: s1Bk0(O+2)  P7: s1Ak0(O+2)
// vmcnt before closing barrier (per-wave drain + joint barrier = visibility):
//   end-P4: vmcnt(8)  [drains prevP6,7 = s1k0]   end-P6: vmcnt(10) [drains P1]
//   end-P8: vmcnt(4)  [drains P2,P3,P5 = tile E+2]
// Prologue: tile0 all + tile1-k0 (12 loads) -> vmcnt(4) -> barrier.
// Last iteration peeled (no stages except P1; waits 4/0/none).
// ---------------------------------------------------------------------------
__global__ __launch_bounds__(512, 1) void gemm256_8ph(const ushort_t* __restrict__ A,
                                                      const ushort_t* __restrict__ Bt,
                                                      ushort_t* __restrict__ C,
                                                      int nbn, int N) {
    extern __shared__ __align__(16) ushort_t lds[];

    const int t    = threadIdx.x;
    const int wave = t >> 6;
    const int lane = t & 63;
    const int wr   = wave >> 2;       // 0..1
    const int wc   = wave & 3;        // 0..3
    const int lhi  = lane >> 4;       // 0..3
    const int llo  = lane & 15;       // 0..15

    // XCD-aware bijective swizzle (512 % 8 == 0)
    const int cpx = gridDim.x >> 3;
    const int swz = (blockIdx.x & 7) * cpx + (blockIdx.x >> 3);
    const int m0  = (swz / nbn) * 256;
    const int n0  = (swz % nbn) * 256;

    // stage half-tile (mat, khalf) of K-tile kt: 2 gloads/thread (256 rows x 32)
    #define STAGE(mat, gptr, g0, kt, kh)                                              \
        _Pragma("unroll")                                                             \
        for (int j = 0; j < 2; ++j) {                                                 \
            const int row_ = j * 128 + (t >> 2);                                      \
            const int sl_  = (t & 3) ^ ((row_ >> 1) & 3);                             \
            gload_lds16((gptr) + (size_t)((g0) + row_) * GK + (kt) * 64 + (kh) * 32   \
                            + sl_ * 8,                                                \
                        lds + (((((kt) & 1) * 2 + (mat)) * 2 + (kh)) * 8192)          \
                            + (j * 128 + (wave << 4)) * 32);                          \
        }

    f32x4 acc[8][4] = {};
    bf16x8 bfr[4];

    // phase: reads (s,kh) quadrant mh; optional B-frag reload; stages; end-wait
    #define DO_PHASE(s_, kh_, mh_, READB, STAGE_OPS, ENDWAIT)                          \
    {                                                                                  \
        if (READB) {                                                                   \
            _Pragma("unroll")                                                          \
            for (int n = 0; n < 4; ++n) {                                              \
                const int row = wc * 64 + n * 16 + llo;                                \
                bfr[n] = *(const bf16x8*)&lds[((((s_) * 2 + 1) * 2 + (kh_)) * 8192)    \
                             + row * 32 + ((lhi ^ ((row >> 1) & 3)) << 3)];            \
            }                                                                          \
        }                                                                              \
        bf16x8 afr[4];                                                                 \
        _Pragma("unroll")                                                              \
        for (int mi = 0; mi < 4; ++mi) {                                               \
            const int row = wr * 128 + ((mh_) * 4 + mi) * 16 + llo;                    \
            afr[mi] = *(const bf16x8*)&lds[((((s_) * 2 + 0) * 2 + (kh_)) * 8192)       \
                           + row * 32 + ((lhi ^ ((row >> 1) & 3)) << 3)];              \
        }                                                                              \
        STAGE_OPS;                                                                     \
        __builtin_amdgcn_s_barrier();                                                  \
        asm volatile("s_waitcnt lgkmcnt(0)" ::: "memory");                             \
        __builtin_amdgcn_sched_barrier(0);                                             \
        __builtin_amdgcn_s_setprio(1);                                                 \
        _Pragma("unroll")                                                              \
        for (int mi = 0; mi < 4; ++mi)                                                 \
            _Pragma("unroll")                                                          \
            for (int n = 0; n < 4; ++n)                                                \
                acc[(mh_) * 4 + mi][n] = __builtin_amdgcn_mfma_f32_16x16x32_bf16(      \
                    afr[mi], bfr[n], acc[(mh_) * 4 + mi][n], 0, 0, 0);                 \
        __builtin_amdgcn_s_setprio(0);                                                 \
        ENDWAIT;                                                                       \
        __builtin_amdgcn_s_barrier();                                                  \
    }

    #define VM(n) asm volatile("s_waitcnt vmcnt(" #n ")" ::: "memory")

    // ---- prologue: tile0 (slot0, all) + tile1 (slot1, k0) = 12 loads ----
    STAGE(1, Bt, n0, 0, 0); STAGE(0, A, m0, 0, 0);
    STAGE(1, Bt, n0, 0, 1); STAGE(0, A, m0, 0, 1);
    STAGE(1, Bt, n0, 1, 0); STAGE(0, A, m0, 1, 0);
    VM(4);                              // tile0 landed; tile1-k0 in flight
    __builtin_amdgcn_s_barrier();

    for (int i = 0; i + 1 < NI; ++i) {
        const int O = 2 * i + 1;
        const int E2 = 2 * i + 2, O2 = 2 * i + 3;
        DO_PHASE(0, 0, 0, 1, { STAGE(1, Bt, n0, O, 1); STAGE(0, A, m0, O, 1); }, )
        DO_PHASE(0, 0, 1, 0, { STAGE(1, Bt, n0, E2, 0); }, )
        DO_PHASE(0, 1, 0, 1, { STAGE(0, A, m0, E2, 0); }, )
        DO_PHASE(0, 1, 1, 0, { }, VM(8))
        DO_PHASE(1, 0, 0, 1, { STAGE(1, Bt, n0, E2, 1); STAGE(0, A, m0, E2, 1); }, )
        DO_PHASE(1, 0, 1, 0, { STAGE(1, Bt, n0, O2, 0); }, VM(10))
        DO_PHASE(1, 1, 0, 1, { STAGE(0, A, m0, O2, 0); }, )
        DO_PHASE(1, 1, 1, 0, { }, VM(4))
    }
    // ---- peeled last iteration (E=14, O=15) ----
    DO_PHASE(0, 0, 0, 1, { STAGE(1, Bt, n0, 15, 1); STAGE(0, A, m0, 15, 1); }, )
    DO_PHASE(0, 0, 1, 0, { }, )
    DO_PHASE(0, 1, 0, 1, { }, )
    DO_PHASE(0, 1, 1, 0, { }, VM(4))
    DO_PHASE(1, 0, 0, 1, { }, )
    DO_PHASE(1, 0, 1, 0, { }, VM(0))
    DO_PHASE(1, 1, 0, 1, { }, )
    DO_PHASE(1, 1, 1, 0, { }, )

    #undef DO_PHASE
    #undef STAGE
    #undef VM

    // ---- epilogue: C write (bf16) ----
    #pragma unroll
    for (int mi = 0; mi < 8; ++mi) {
        #pragma unroll
        for (int n = 0; n < 4; ++n) {
            const int col = n0 + wc * 64 + n * 16 + llo;
            #pragma unroll
            for (int i = 0; i < 4; ++i) {
                const int row = m0 + wr * 128 + mi * 16 + lhi * 4 + i;
                C[(size_t)row * N + col] = f2bf(acc[mi][n][i]);
            }
        }
    }
}

// ---------------------------------------------------------------------------
// MFMA fused attention, swapped-operand (S^T) form, Gaussian band skip +
// T14 async-STAGE (validated rounds 7-9, unchanged).
// ---------------------------------------------------------------------------
__global__ __launch_bounds__(256) void attn_mfma(const ushort_t* __restrict__ qkv,
                                                 const int* __restrict__ mask,
                                                 const int* __restrict__ qmask,
                                                 const float* __restrict__ shiftp,
                                                 const float* __restrict__ biasp,
                                                 const int* __restrict__ useg,
                                                 ushort_t* __restrict__ O) {
    __shared__ __align__(16) ushort_t K1s[KB_][LDP];
    __shared__ __align__(16) ushort_t K2s[KB_][LDP];
    __shared__ __align__(16) ushort_t Vt[DH_][LDP];    // [d][kv]
    __shared__ __align__(16) unsigned Ps32[QB_][36];   // P^T packed pairs / O out
    __shared__ __align__(16) int      Ms[L_];          // (qmask<<1)|mask per key

    const int t    = threadIdx.x;
    const int wave = t >> 6;
    const int lane = t & 63;
    const int lhi  = lane >> 4;     // 0..3
    const int llo  = lane & 15;     // 0..15

    const int orig = blockIdx.x;
    const int swz  = (orig & 7) * 256 + (orig >> 3);
    const int bh   = swz >> 3;
    const int qb   = swz & 7;
    const int b    = bh >> 4;
    const int h    = bh & 15;
    const int q0   = qb * QB_;

    const float shiftv = shiftp[0];
    const float biasv  = biasp[0];
    const int   useG   = useg[0];
    const size_t rowbase = (size_t)b * L_ * (4 * D_);
    const int    hoff    = h * DH_;

    {
        const int k = t;
        Ms[k]       = (qmask[b * L_ + k] << 1) | (mask[b * L_ + k] != 0 ? 1 : 0);
        Ms[k + 256] = (qmask[b * L_ + k + 256] << 1) | (mask[b * L_ + k + 256] != 0 ? 1 : 0);
    }

    const int gq = q0 + wave * 16 + llo;
    bf16x8 af_q[2];
    #pragma unroll
    for (int ks = 0; ks < 2; ++ks)
        af_q[ks] = *(const bf16x8*)&qkv[rowbase + (size_t)gq * (4 * D_) + hoff
                                        + ks * 32 + lhi * 8];
    const int qm_q = qmask[b * L_ + gq];

    int lo = 0, hi = (L_ / KB_) - 1;
    if (useG) {
        while (lo < hi) {
            const int k0 = lo * KB_;
            int dmin = (k0 > q0) ? (k0 - (q0 + KB_ - 1)) : (q0 - (k0 + KB_ - 1));
            if (dmin < 0) dmin = 0;
            if (shiftv * (float)dmin * (float)dmin > 240.f) ++lo; else break;
        }
        while (hi > lo) {
            const int k0 = hi * KB_;
            int dmin = (k0 > q0) ? (k0 - (q0 + KB_ - 1)) : (q0 - (k0 + KB_ - 1));
            if (dmin < 0) dmin = 0;
            if (shiftv * (float)dmin * (float)dmin > 240.f) --hi; else break;
        }
    }

    float m_run = -1e30f, l_run = 0.f;
    f32x4 acc_o[4] = {};

    const int srow8 = t >> 3;
    const int scol8 = (t & 7) * 8;
    const int vkv   = t & 63;
    const int vd0   = (t >> 6) * 8;

    uint4 pk1[2], pk2[2], pvv[2];

    #define ISSUE_KV(kt_) do {                                                          \
        const int k0_ = (kt_) * KB_;                                                    \
        _Pragma("unroll")                                                               \
        for (int it = 0; it < 2; ++it) {                                                \
            const int row = srow8 + it * 32;                                            \
            const size_t gb = rowbase + (size_t)(k0_ + row) * (4 * D_) + hoff + scol8;  \
            pk1[it] = *(const uint4*)&qkv[gb + D_];                                     \
            pk2[it] = *(const uint4*)&qkv[gb + 2 * D_];                                 \
            const int d_ = vd0 + it * 32;                                               \
            pvv[it] = *(const uint4*)&qkv[rowbase + (size_t)(k0_ + vkv) * (4 * D_)      \
                                          + 3 * D_ + hoff + d_];                        \
        }                                                                               \
    } while (0)

    ISSUE_KV(lo);

    for (int kt = lo; kt <= hi; ++kt) {
        const int k0 = kt * KB_;

        #pragma unroll
        for (int it = 0; it < 2; ++it) {
            const int row = srow8 + it * 32;
            *(uint4*)&K1s[row][scol8] = pk1[it];
            *(uint4*)&K2s[row][scol8] = pk2[it];
            const int d = vd0 + it * 32;
            const uint4 raw = pvv[it];
            Vt[d + 0][vkv] = (ushort_t)(raw.x & 0xFFFFu);
            Vt[d + 1][vkv] = (ushort_t)(raw.x >> 16);
            Vt[d + 2][vkv] = (ushort_t)(raw.y & 0xFFFFu);
            Vt[d + 3][vkv] = (ushort_t)(raw.y >> 16);
            Vt[d + 4][vkv] = (ushort_t)(raw.z & 0xFFFFu);
            Vt[d + 5][vkv] = (ushort_t)(raw.z >> 16);
            Vt[d + 6][vkv] = (ushort_t)(raw.w & 0xFFFFu);
            Vt[d + 7][vkv] = (ushort_t)(raw.w >> 16);
        }
        if (kt < hi) ISSUE_KV(kt + 1);
        __syncthreads();

        f32x4 s1[4], s2[4];
        #pragma unroll
        for (int n = 0; n < 4; ++n) { s1[n] = (f32x4){0,0,0,0}; s2[n] = (f32x4){0,0,0,0}; }
        #pragma unroll
        for (int ks = 0; ks < 2; ++ks) {
            const int kb = ks * 32 + lhi * 8;
            #pragma unroll
            for (int n = 0; n < 4; ++n) {
                const bf16x8 bk1 = *(const bf16x8*)&K1s[n * 16 + llo][kb];
                const bf16x8 bk2 = *(const bf16x8*)&K2s[n * 16 + llo][kb];
                s1[n] = __builtin_amdgcn_mfma_f32_16x16x32_bf16(bk1, af_q[ks], s1[n], 0, 0, 0);
                s2[n] = __builtin_amdgcn_mfma_f32_16x16x32_bf16(bk2, af_q[ks], s2[n], 0, 0, 0);
            }
        }

        float sv[4][4];
        float mx = -1e30f;
        #pragma unroll
        for (int n = 0; n < 4; ++n) {
            const int4 mc = *(const int4*)&Ms[k0 + n * 16 + lhi * 4];
            const int mci[4] = {mc.x, mc.y, mc.z, mc.w};
            #pragma unroll
            for (int i = 0; i < 4; ++i) {
                const int key = k0 + n * 16 + lhi * 4 + i;
                float x = ((mci[i] >> 1) == qm_q) ? s1[n][i] : s2[n][i];
                if (!(mci[i] & 1)) x = NEG_;
                if (useG) {
                    const float dq = (float)(gq - key);
                    x -= shiftv * dq * dq + biasv;
                }
                sv[n][i] = x;
                mx = fmaxf(mx, x);
            }
        }
        mx = fmaxf(mx, __shfl_xor(mx, 16));
        mx = fmaxf(mx, __shfl_xor(mx, 32));

        const float m_new = fmaxf(m_run, mx);
        const float scale = __expf(m_run - m_new);

        float p[4][4], ls = 0.f;
        #pragma unroll
        for (int n = 0; n < 4; ++n)
            #pragma unroll
            for (int i = 0; i < 4; ++i) {
                p[n][i] = __expf(sv[n][i] - m_new);
                ls += p[n][i];
            }
        ls += __shfl_xor(ls, 16);
        ls += __shfl_xor(ls, 32);
        l_run = l_run * scale + ls;
        m_run = m_new;

        #pragma unroll
        for (int n2 = 0; n2 < 4; ++n2) {
            acc_o[n2][0] *= scale; acc_o[n2][1] *= scale;
            acc_o[n2][2] *= scale; acc_o[n2][3] *= scale;
        }

        const int qrow = wave * 16 + llo;
        #pragma unroll
        for (int n = 0; n < 4; ++n) {
            uint2 w;
            w.x = packbf(p[n][0], p[n][1]);
            w.y = packbf(p[n][2], p[n][3]);
            *(uint2*)&Ps32[qrow][n * 8 + lhi * 2] = w;
        }

        #pragma unroll
        for (int ks = 0; ks < 2; ++ks) {
            const int kb = ks * 32 + lhi * 8;
            const bf16x8 bp = *(const bf16x8*)&Ps32[qrow][ks * 16 + lhi * 4];
            #pragma unroll
            for (int n2 = 0; n2 < 4; ++n2) {
                const bf16x8 av = *(const bf16x8*)&Vt[n2 * 16 + llo][kb];
                acc_o[n2] = __builtin_amdgcn_mfma_f32_16x16x32_bf16(av, bp, acc_o[n2], 0, 0, 0);
            }
        }
        __syncthreads();
    }
    #undef ISSUE_KV

    {
        const float inv = 1.f / l_run;
        const int qrow = wave * 16 + llo;
        #pragma unroll
        for (int n2 = 0; n2 < 4; ++n2) {
            uint2 w;
            w.x = packbf(acc_o[n2][0] * inv, acc_o[n2][1] * inv);
            w.y = packbf(acc_o[n2][2] * inv, acc_o[n2][3] * inv);
            *(uint2*)&Ps32[qrow][n2 * 8 + lhi * 2] = w;
        }
    }
    __syncthreads();
    {
        const int row = t >> 2;
        const int c4  = (t & 3) * 8;
        const uint4 a = *(const uint4*)&Ps32[row][c4];
        const uint4 b2 = *(const uint4*)&Ps32[row][c4 + 4];
        ushort_t* dst = &O[(size_t)(b * L_ + q0 + row) * D_ + hoff + c4 * 2];
        *(uint4*)dst       = a;
        *(uint4*)(dst + 8) = b2;
    }
}

// ---------------------------------------------------------------------------
// Launch
// ---------------------------------------------------------------------------
extern "C" void kernel_launch(void* const* d_in, const int* in_sizes, int n_in,
                              void* d_out, int out_size, void* d_ws, size_t ws_size,
                              hipStream_t stream) {
    const float* x      = (const float*)d_in[0];
    const int*   mask   = (const int*)d_in[1];
    const int*   qmask  = (const int*)d_in[2];
    const float* Wqkv   = (const float*)d_in[3];
    const float* Wfc    = (const float*)d_in[4];
    const float* bfc    = (const float*)d_in[5];
    const float* shift  = (const float*)d_in[6];
    const float* bias_p = (const float*)d_in[7];
    const int*   useg   = (const int*)d_in[8];
    float*       out    = (float*)d_out;

    const int M  = B_ * L_;         // 8192
    const int N1 = 4 * D_;          // 4096

    ushort_t* qkv = (ushort_t*)d_ws;
    ushort_t* Obf = qkv + (size_t)M * N1;
    ushort_t* xbf = Obf + (size_t)M * D_;
    ushort_t* WqT = xbf + (size_t)M * D_;
    ushort_t* WfT = WqT + (size_t)N1 * D_;

    prep_all<<<dim3(8192 + 4096 + 1024), 256, 0, stream>>>(x, Wqkv, Wfc,
                                                           xbf, WqT, WfT);

    // Stage 1: qkv = x @ Wqkv — 256x256 8-phase kernel (512 blocks, 128 KiB LDS)
    gemm256_8ph<<<dim3((M / 256) * (N1 / 256)), 512, 131072, stream>>>(
        xbf, WqT, qkv, N1 / 256, N1);

    // Stage 2: fused attention (Gaussian band + async-stage) -> Obf
    attn_mfma<<<dim3((B_ * H_) * (L_ / QB_)), 256, 0, stream>>>(qkv, mask, qmask,
                                                                shift, bias_p, useg, Obf);

    // Stage 3: out = Obf @ Wfc + bfc  (128x128 swizzled kernel: 512 blocks)
    gemm_bf16_mfma<<<dim3(D_ / 128, M / 128), 256, 0, stream>>>(
        Obf, WfT, bfc, out, M, D_, D_);
}

// Round 11
// 159.586 us; speedup vs baseline: 1.1042x; 1.0559x over previous
//
#include <hip/hip_runtime.h>
#include <hip/hip_bf16.h>

// Problem constants
#define B_  16
#define L_  512
#define D_  1024
#define H_  16
#define DH_ 64
#define NEG_ (-1e9f)
#define QB2 32
#define KB2 32
#define LDP 72    // padded LDS row (bf16) for attention K tiles

#define GK  1024  // K dim of both GEMMs
#define NT  32    // GK/32 K-tiles for the BK=32 stage-1 GEMM

typedef unsigned short ushort_t;
typedef __attribute__((ext_vector_type(8))) short bf16x8;
typedef __attribute__((ext_vector_type(4))) float f32x4;

__device__ __forceinline__ ushort_t f2bf(float f) {
    unsigned u = __float_as_uint(f);
    u += 0x7FFFu + ((u >> 16) & 1u);   // round-to-nearest-even
    return (ushort_t)(u >> 16);
}
__device__ __forceinline__ unsigned packbf(float a, float b) {
    return (unsigned)f2bf(a) | ((unsigned)f2bf(b) << 16);
}

__device__ __forceinline__ void gload_lds16(const void* g, void* l) {
    __builtin_amdgcn_global_load_lds(
        (const __attribute__((address_space(1))) void*)g,
        (__attribute__((address_space(3))) void*)l, 16, 0, 0);
}

// ---------------------------------------------------------------------------
// Merged prep: x f32->bf16  +  transpose Wqkv  +  transpose Wfc (one dispatch)
// ---------------------------------------------------------------------------
__global__ __launch_bounds__(256) void prep_all(const float* __restrict__ x,
                                                const float* __restrict__ Wqkv,
                                                const float* __restrict__ Wfc,
                                                ushort_t* __restrict__ xbf,
                                                ushort_t* __restrict__ WqT,
                                                ushort_t* __restrict__ WfT) {
    __shared__ float tile[32][33];
    const int bid = blockIdx.x;
    const int t   = threadIdx.x;

    if (bid < 8192) {   // conv x -> xbf
        const int i = (bid * 256 + t) * 4;
        const float4 v = *(const float4*)&x[i];
        ushort4 o;
        o.x = f2bf(v.x); o.y = f2bf(v.y); o.z = f2bf(v.z); o.w = f2bf(v.w);
        *(ushort4*)&xbf[i] = o;
        return;
    }
    const float* src; ushort_t* dst; int C, gx, gy;
    if (bid < 8192 + 4096) {
        const int lb = bid - 8192;
        src = Wqkv; dst = WqT; C = 4096; gx = lb & 127; gy = lb >> 7;
    } else {
        const int lb = bid - 12288;
        src = Wfc;  dst = WfT; C = 1024; gx = lb & 31;  gy = lb >> 5;
    }
    const int R  = 1024;
    const int r0 = gy * 32, c0 = gx * 32;
    const int tr = t >> 3, tc = (t & 7) * 4;
    const float4 v = *(const float4*)&src[(size_t)(r0 + tr) * C + c0 + tc];
    tile[tr][tc + 0] = v.x;
    tile[tr][tc + 1] = v.y;
    tile[tr][tc + 2] = v.z;
    tile[tr][tc + 3] = v.w;
    __syncthreads();
    ushort4 o;
    o.x = f2bf(tile[tc + 0][tr]);
    o.y = f2bf(tile[tc + 1][tr]);
    o.z = f2bf(tile[tc + 2][tr]);
    o.w = f2bf(tile[tc + 3][tr]);
    *(ushort4*)&dst[(size_t)(c0 + tr) * R + r0 + tc] = o;
}

// ---------------------------------------------------------------------------
// Stage-3 GEMM (128x128, BK=64) with row-XOR LDS swizzle (validated r9/r10).
// ---------------------------------------------------------------------------
__global__ __launch_bounds__(256) void gemm_bf16_mfma(const ushort_t* __restrict__ A,
                                                      const ushort_t* __restrict__ Bt,
                                                      const float* __restrict__ bias,
                                                      float* __restrict__ C,
                                                      int M, int N, int K) {
    __shared__ __align__(16) ushort_t As[128 * 64];
    __shared__ __align__(16) ushort_t Bs[128 * 64];

    const int t    = threadIdx.x;
    const int wave = t >> 6;
    const int lane = t & 63;
    const int m0   = blockIdx.y * 128;
    const int n0   = blockIdx.x * 128;
    const int wr   = wave >> 1;
    const int wc   = wave & 1;

    const int lrow = lane >> 3;
    const int ksl  = (lane & 7) ^ lrow;
    const int llo  = lane & 15;
    const int lhi  = lane >> 4;

    f32x4 acc[4][4] = {};

    for (int k0 = 0; k0 < K; k0 += 64) {
        #pragma unroll
        for (int i = 0; i < 4; ++i) {
            const int row = wave * 32 + i * 8;
            gload_lds16(A + (size_t)(m0 + row + lrow) * K + k0 + ksl * 8,
                        As + (size_t)row * 64);
            gload_lds16(Bt + (size_t)(n0 + row + lrow) * K + k0 + ksl * 8,
                        Bs + (size_t)row * 64);
        }
        __syncthreads();

        #pragma unroll
        for (int ks = 0; ks < 2; ++ks) {
            bf16x8 af[4], bfr[4];
            #pragma unroll
            for (int m = 0; m < 4; ++m) {
                const int row = wr * 64 + m * 16 + llo;
                af[m] = *(const bf16x8*)&As[row * 64 + (((ks * 4 + lhi) ^ (row & 7)) << 3)];
            }
            #pragma unroll
            for (int n = 0; n < 4; ++n) {
                const int row = wc * 64 + n * 16 + llo;
                bfr[n] = *(const bf16x8*)&Bs[row * 64 + (((ks * 4 + lhi) ^ (row & 7)) << 3)];
            }
            #pragma unroll
            for (int m = 0; m < 4; ++m)
                #pragma unroll
                for (int n = 0; n < 4; ++n)
                    acc[m][n] = __builtin_amdgcn_mfma_f32_16x16x32_bf16(
                        af[m], bfr[n], acc[m][n], 0, 0, 0);
        }
        __syncthreads();
    }

    #pragma unroll
    for (int m = 0; m < 4; ++m) {
        #pragma unroll
        for (int n = 0; n < 4; ++n) {
            const int col = n0 + wc * 64 + n * 16 + llo;
            const float bv = bias[col];
            #pragma unroll
            for (int i = 0; i < 4; ++i) {
                const int row = m0 + wr * 64 + m * 16 + lhi * 4 + i;
                C[(size_t)row * N + col] = acc[m][n][i] + bv;
            }
        }
    }
}

// ---------------------------------------------------------------------------
// Stage-1 GEMM: round-8 free-running 256x256 kernel (best measured: 80 us).
// BK=32, 512 threads = 8 waves, 4 LDS buffers, 2-tile-ahead prefetch,
// counted vmcnt(4), ONE barrier per K-tile, XOR-swizzled LDS (both sides).
// ---------------------------------------------------------------------------
__device__ __forceinline__ bf16x8 frag_ld(const ushort_t* tile, int row, int lhi) {
    const int slot = lhi ^ ((row >> 1) & 3);
    return *(const bf16x8*)&tile[row * 32 + (slot << 3)];
}

__global__ __launch_bounds__(512, 2) void gemm256_8p(const ushort_t* __restrict__ A,
                                                     const ushort_t* __restrict__ Bt,
                                                     ushort_t* __restrict__ C,
                                                     int nbn, int N) {
    extern __shared__ __align__(16) ushort_t lds[];   // 4 bufs x {A,B} x 256x32

    const int t    = threadIdx.x;
    const int wave = t >> 6;
    const int lane = t & 63;
    const int wr   = wave >> 2;       // 0..1
    const int wc   = wave & 3;        // 0..3
    const int lhi  = lane >> 4;       // 0..3
    const int llo  = lane & 15;       // 0..15
    const int srow  = lane >> 2;                       // 0..15
    const int sslot = (lane & 3) ^ ((lane >> 3) & 3);  // pre-swizzled source slot

    // XCD-aware bijective swizzle (grid % 8 == 0)
    const int cpx = gridDim.x >> 3;
    const int swz = (blockIdx.x & 7) * cpx + (blockIdx.x >> 3);
    const int m0  = (swz / nbn) * 256;
    const int n0  = (swz % nbn) * 256;

    #define STAGE_H(mat, gptr, grow0, kt, half)                                         \
        gload_lds16((gptr) + (size_t)((grow0) + (half) * 128 + (wave << 4) + srow) * GK \
                        + (kt) * 32 + (sslot << 3),                                     \
                    lds + ((((kt) & 3) * 2 + (mat)) * 8192                              \
                           + ((half) * 128 + (wave << 4)) * 32))

    f32x4 acc[8][4] = {};

    STAGE_H(0, A,  m0, 0, 0); STAGE_H(0, A,  m0, 0, 1);
    STAGE_H(1, Bt, n0, 0, 0); STAGE_H(1, Bt, n0, 0, 1);
    STAGE_H(0, A,  m0, 1, 0); STAGE_H(0, A,  m0, 1, 1);
    STAGE_H(1, Bt, n0, 1, 0); STAGE_H(1, Bt, n0, 1, 1);
    asm volatile("s_waitcnt vmcnt(4)" ::: "memory");
    __builtin_amdgcn_s_barrier();

    for (int kt = 0; kt < NT; ++kt) {
        const ushort_t* At  = lds + ((kt & 3) * 2 + 0) * 8192;
        const ushort_t* Bti = lds + ((kt & 3) * 2 + 1) * 8192;

        bf16x8 afr[4], bfr[4];

        #pragma unroll
        for (int n = 0; n < 4; ++n)
            bfr[n] = frag_ld(Bti, wc * 64 + n * 16 + llo, lhi);
        #pragma unroll
        for (int mi = 0; mi < 4; ++mi)
            afr[mi] = frag_ld(At, wr * 128 + mi * 16 + llo, lhi);
        if (kt + 2 < NT) {
            STAGE_H(0, A, m0, kt + 2, 0);
            STAGE_H(0, A, m0, kt + 2, 1);
        }
        __builtin_amdgcn_s_setprio(1);
        #pragma unroll
        for (int mi = 0; mi < 4; ++mi)
            #pragma unroll
            for (int n = 0; n < 4; ++n)
                acc[mi][n] = __builtin_amdgcn_mfma_f32_16x16x32_bf16(
                    afr[mi], bfr[n], acc[mi][n], 0, 0, 0);
        __builtin_amdgcn_s_setprio(0);

        #pragma unroll
        for (int mi = 0; mi < 4; ++mi)
            afr[mi] = frag_ld(At, wr * 128 + (mi + 4) * 16 + llo, lhi);
        if (kt + 2 < NT) {
            STAGE_H(1, Bt, n0, kt + 2, 0);
            STAGE_H(1, Bt, n0, kt + 2, 1);
        }
        __builtin_amdgcn_s_setprio(1);
        #pragma unroll
        for (int mi = 0; mi < 4; ++mi)
            #pragma unroll
            for (int n = 0; n < 4; ++n)
                acc[mi + 4][n] = __builtin_amdgcn_mfma_f32_16x16x32_bf16(
                    afr[mi], bfr[n], acc[mi + 4][n], 0, 0, 0);
        __builtin_amdgcn_s_setprio(0);

        if (kt + 2 < NT)      { asm volatile("s_waitcnt vmcnt(4)" ::: "memory"); }
        else if (kt + 1 < NT) { asm volatile("s_waitcnt vmcnt(0)" ::: "memory"); }
        __builtin_amdgcn_s_barrier();
    }
    #undef STAGE_H

    #pragma unroll
    for (int mi = 0; mi < 8; ++mi) {
        #pragma unroll
        for (int n = 0; n < 4; ++n) {
            const int col = n0 + wc * 64 + n * 16 + llo;
            #pragma unroll
            for (int i = 0; i < 4; ++i) {
                const int row = m0 + wr * 128 + mi * 16 + lhi * 4 + i;
                C[(size_t)row * N + col] = f2bf(acc[mi][n][i]);
            }
        }
    }
}

// ---------------------------------------------------------------------------
// MFMA fused attention, swapped-operand (S^T) form, QB=KB=32, 128 threads =
// 2 waves (each owns 16 q-rows).  Halves band overlap waste vs QB=KB=64:
// per-query processed keys ~96 vs ~192 at shift~0.8.  Gaussian band skip +
// T14 async-STAGE retained.  Fragment algebra identical to the validated
// 64-wide version with n-frags 4->2 (S^T) and PV K-steps 2->1.
// ---------------------------------------------------------------------------
__global__ __launch_bounds__(128) void attn_mfma(const ushort_t* __restrict__ qkv,
                                                 const int* __restrict__ mask,
                                                 const int* __restrict__ qmask,
                                                 const float* __restrict__ shiftp,
                                                 const float* __restrict__ biasp,
                                                 const int* __restrict__ useg,
                                                 ushort_t* __restrict__ O) {
    __shared__ __align__(16) ushort_t K1s[KB2][LDP];
    __shared__ __align__(16) ushort_t K2s[KB2][LDP];
    __shared__ __align__(16) ushort_t Vt[DH_][36];     // [d][kv], kv=32 + pad
    __shared__ __align__(16) unsigned Ps32[QB2][36];   // P^T packed pairs / O out
    __shared__ __align__(16) int      Ms[L_];          // (qmask<<1)|mask per key

    const int t    = threadIdx.x;
    const int wave = t >> 6;        // 0..1
    const int lane = t & 63;
    const int lhi  = lane >> 4;     // 0..3
    const int llo  = lane & 15;     // 0..15

    // XCD-aware bijective swizzle (4096 % 8 == 0)
    const int orig = blockIdx.x;
    const int swz  = (orig & 7) * 512 + (orig >> 3);
    const int bh   = swz >> 4;            // 0..255
    const int qb   = swz & 15;            // 0..15
    const int b    = bh >> 4;
    const int h    = bh & 15;
    const int q0   = qb * QB2;

    const float shiftv = shiftp[0];
    const float biasv  = biasp[0];
    const int   useG   = useg[0];
    const size_t rowbase = (size_t)b * L_ * (4 * D_);
    const int    hoff    = h * DH_;

    // preload key mask codes for this b (4 per thread)
    #pragma unroll
    for (int j = 0; j < 4; ++j) {
        const int k = t + j * 128;
        Ms[k] = (qmask[b * L_ + k] << 1) | (mask[b * L_ + k] != 0 ? 1 : 0);
    }

    // Q B-fragments straight from global (K-contiguous)
    const int gq = q0 + wave * 16 + llo;
    bf16x8 af_q[2];
    #pragma unroll
    for (int ks = 0; ks < 2; ++ks)
        af_q[ks] = *(const bf16x8*)&qkv[rowbase + (size_t)gq * (4 * D_) + hoff
                                        + ks * 32 + lhi * 8];
    const int qm_q = qmask[b * L_ + gq];

    // Gaussian band: contiguous surviving kt range [lo, hi]
    int lo = 0, hi = (L_ / KB2) - 1;
    if (useG) {
        while (lo < hi) {
            const int k0 = lo * KB2;
            int dmin = (k0 > q0) ? (k0 - (q0 + QB2 - 1)) : (q0 - (k0 + KB2 - 1));
            if (dmin < 0) dmin = 0;
            if (shiftv * (float)dmin * (float)dmin > 240.f) ++lo; else break;
        }
        while (hi > lo) {
            const int k0 = hi * KB2;
            int dmin = (k0 > q0) ? (k0 - (q0 + QB2 - 1)) : (q0 - (k0 + KB2 - 1));
            if (dmin < 0) dmin = 0;
            if (shiftv * (float)dmin * (float)dmin > 240.f) --hi; else break;
        }
    }

    float m_run = -1e30f, l_run = 0.f;
    f32x4 acc_o[4] = {};   // O^T frags: col=q=llo, row d = n2*16 + lhi*4 + i

    // staging index constants (128 threads)
    const int srow = t >> 2;          // 0..31 (K rows)
    const int scol = (t & 3) * 8;     // 0,8,16,24 (+32 for second chunk)
    const int vkv  = t & 31;          // V row (key)
    const int vd0  = (t >> 5) * 8;    // 0,8,16,24 (+32 for second chunk)

    uint4 pk1[2], pk2[2], pvv[2];

    #define ISSUE_KV(kt_) do {                                                          \
        const int k0_ = (kt_) * KB2;                                                    \
        _Pragma("unroll")                                                               \
        for (int it = 0; it < 2; ++it) {                                                \
            const size_t gb = rowbase + (size_t)(k0_ + srow) * (4 * D_) + hoff          \
                              + scol + it * 32;                                         \
            pk1[it] = *(const uint4*)&qkv[gb + D_];                                     \
            pk2[it] = *(const uint4*)&qkv[gb + 2 * D_];                                 \
            pvv[it] = *(const uint4*)&qkv[rowbase + (size_t)(k0_ + vkv) * (4 * D_)      \
                                          + 3 * D_ + hoff + vd0 + it * 32];             \
        }                                                                               \
    } while (0)

    ISSUE_KV(lo);

    for (int kt = lo; kt <= hi; ++kt) {
        const int k0 = kt * KB2;

        // write staged regs -> LDS
        #pragma unroll
        for (int it = 0; it < 2; ++it) {
            *(uint4*)&K1s[srow][scol + it * 32] = pk1[it];
            *(uint4*)&K2s[srow][scol + it * 32] = pk2[it];
            const int d = vd0 + it * 32;
            const uint4 raw = pvv[it];
            Vt[d + 0][vkv] = (ushort_t)(raw.x & 0xFFFFu);
            Vt[d + 1][vkv] = (ushort_t)(raw.x >> 16);
            Vt[d + 2][vkv] = (ushort_t)(raw.y & 0xFFFFu);
            Vt[d + 3][vkv] = (ushort_t)(raw.y >> 16);
            Vt[d + 4][vkv] = (ushort_t)(raw.z & 0xFFFFu);
            Vt[d + 5][vkv] = (ushort_t)(raw.z >> 16);
            Vt[d + 6][vkv] = (ushort_t)(raw.w & 0xFFFFu);
            Vt[d + 7][vkv] = (ushort_t)(raw.w >> 16);
        }
        if (kt < hi) ISSUE_KV(kt + 1);
        __syncthreads();

        // S^T = mfma(K-frag, Q-frag): rows = keys (32), cols = q
        f32x4 s1[2], s2[2];
        #pragma unroll
        for (int n = 0; n < 2; ++n) { s1[n] = (f32x4){0,0,0,0}; s2[n] = (f32x4){0,0,0,0}; }
        #pragma unroll
        for (int ks = 0; ks < 2; ++ks) {
            const int kb = ks * 32 + lhi * 8;
            #pragma unroll
            for (int n = 0; n < 2; ++n) {
                const bf16x8 bk1 = *(const bf16x8*)&K1s[n * 16 + llo][kb];
                const bf16x8 bk2 = *(const bf16x8*)&K2s[n * 16 + llo][kb];
                s1[n] = __builtin_amdgcn_mfma_f32_16x16x32_bf16(bk1, af_q[ks], s1[n], 0, 0, 0);
                s2[n] = __builtin_amdgcn_mfma_f32_16x16x32_bf16(bk2, af_q[ks], s2[n], 0, 0, 0);
            }
        }

        // select + mask + Gaussian bias; in-lane max
        float sv[2][4];
        float mx = -1e30f;
        #pragma unroll
        for (int n = 0; n < 2; ++n) {
            const int4 mc = *(const int4*)&Ms[k0 + n * 16 + lhi * 4];
            const int mci[4] = {mc.x, mc.y, mc.z, mc.w};
            #pragma unroll
            for (int i = 0; i < 4; ++i) {
                const int key = k0 + n * 16 + lhi * 4 + i;
                float x = ((mci[i] >> 1) == qm_q) ? s1[n][i] : s2[n][i];
                if (!(mci[i] & 1)) x = NEG_;
                if (useG) {
                    const float dq = (float)(gq - key);
                    x -= shiftv * dq * dq + biasv;
                }
                sv[n][i] = x;
                mx = fmaxf(mx, x);
            }
        }
        mx = fmaxf(mx, __shfl_xor(mx, 16));
        mx = fmaxf(mx, __shfl_xor(mx, 32));

        const float m_new = fmaxf(m_run, mx);
        const float scale = __expf(m_run - m_new);

        float p[2][4], ls = 0.f;
        #pragma unroll
        for (int n = 0; n < 2; ++n)
            #pragma unroll
            for (int i = 0; i < 4; ++i) {
                p[n][i] = __expf(sv[n][i] - m_new);
                ls += p[n][i];
            }
        ls += __shfl_xor(ls, 16);
        ls += __shfl_xor(ls, 32);
        l_run = l_run * scale + ls;
        m_run = m_new;

        #pragma unroll
        for (int n2 = 0; n2 < 4; ++n2) {
            acc_o[n2][0] *= scale; acc_o[n2][1] *= scale;
            acc_o[n2][2] *= scale; acc_o[n2][3] *= scale;
        }

        // P^T -> packed u32 pairs -> LDS (wave-private rows, no barrier)
        const int qrow = wave * 16 + llo;
        #pragma unroll
        for (int n = 0; n < 2; ++n) {
            uint2 w;
            w.x = packbf(p[n][0], p[n][1]);
            w.y = packbf(p[n][2], p[n][3]);
            *(uint2*)&Ps32[qrow][n * 8 + lhi * 2] = w;
        }

        // PV: O^T[d][q] += V^T[d][kv] * P^T[kv][q]   (single K=32 step)
        {
            const int kb = lhi * 8;
            const bf16x8 bp = *(const bf16x8*)&Ps32[qrow][lhi * 4];
            #pragma unroll
            for (int n2 = 0; n2 < 4; ++n2) {
                const bf16x8 av = *(const bf16x8*)&Vt[n2 * 16 + llo][kb];
                acc_o[n2] = __builtin_amdgcn_mfma_f32_16x16x32_bf16(av, bp, acc_o[n2], 0, 0, 0);
            }
        }
        __syncthreads();   // protect K/V buffers before next tile's LDS write
    }
    #undef ISSUE_KV

    // epilogue: O^T frags -> LDS (reuse Ps32, wave-private) -> coalesced out
    {
        const float inv = 1.f / l_run;
        const int qrow = wave * 16 + llo;
        #pragma unroll
        for (int n2 = 0; n2 < 4; ++n2) {
            uint2 w;
            w.x = packbf(acc_o[n2][0] * inv, acc_o[n2][1] * inv);
            w.y = packbf(acc_o[n2][2] * inv, acc_o[n2][3] * inv);
            *(uint2*)&Ps32[qrow][n2 * 8 + lhi * 2] = w;
        }
    }
    __syncthreads();
    {
        const int row = t >> 2;             // 0..31
        const int c4  = (t & 3) * 8;        // u32 col
        const uint4 a  = *(const uint4*)&Ps32[row][c4];
        const uint4 b2 = *(const uint4*)&Ps32[row][c4 + 4];
        ushort_t* dst = &O[(size_t)(b * L_ + q0 + row) * D_ + hoff + c4 * 2];
        *(uint4*)dst       = a;
        *(uint4*)(dst + 8) = b2;
    }
}

// ---------------------------------------------------------------------------
// Launch
// ---------------------------------------------------------------------------
extern "C" void kernel_launch(void* const* d_in, const int* in_sizes, int n_in,
                              void* d_out, int out_size, void* d_ws, size_t ws_size,
                              hipStream_t stream) {
    const float* x      = (const float*)d_in[0];
    const int*   mask   = (const int*)d_in[1];
    const int*   qmask  = (const int*)d_in[2];
    const float* Wqkv   = (const float*)d_in[3];
    const float* Wfc    = (const float*)d_in[4];
    const float* bfc    = (const float*)d_in[5];
    const float* shift  = (const float*)d_in[6];
    const float* bias_p = (const float*)d_in[7];
    const int*   useg   = (const int*)d_in[8];
    float*       out    = (float*)d_out;

    const int M  = B_ * L_;         // 8192
    const int N1 = 4 * D_;          // 4096

    ushort_t* qkv = (ushort_t*)d_ws;
    ushort_t* Obf = qkv + (size_t)M * N1;
    ushort_t* xbf = Obf + (size_t)M * D_;
    ushort_t* WqT = xbf + (size_t)M * D_;
    ushort_t* WfT = WqT + (size_t)N1 * D_;

    prep_all<<<dim3(8192 + 4096 + 1024), 256, 0, stream>>>(x, Wqkv, Wfc,
                                                           xbf, WqT, WfT);

    // Stage 1: qkv = x @ Wqkv — round-8 free-running 256x256 kernel (512 blocks)
    gemm256_8p<<<dim3((M / 256) * (N1 / 256)), 512, 131072, stream>>>(
        xbf, WqT, qkv, N1 / 256, N1);

    // Stage 2: fused attention (QB=KB=32, band skip + async-stage) -> Obf
    attn_mfma<<<dim3((B_ * H_) * (L_ / QB2)), 128, 0, stream>>>(qkv, mask, qmask,
                                                                shift, bias_p, useg, Obf);

    // Stage 3: out = Obf @ Wfc + bfc  (128x128 swizzled kernel: 512 blocks)
    gemm_bf16_mfma<<<dim3(D_ / 128, M / 128), 256, 0, stream>>>(
        Obf, WfT, bfc, out, M, D_, D_);
}